// Round 2
// baseline (843.997 us; speedup 1.0000x reference)
//
#include <hip/hip_runtime.h>
#include <hip/hip_bf16.h>
#include <stdint.h>

#define IN_F 4096
#define OUT_F 4096
#define NE 64
#define RD 16
#define BOT 512
#define NTOK 16384

typedef __attribute__((ext_vector_type(8))) short short8;
typedef __attribute__((ext_vector_type(4))) float floatx4;

__device__ __forceinline__ unsigned short f2bf_rne(float f) {
  unsigned int u = __float_as_uint(f);
  return (unsigned short)((u + 0x7FFFu + ((u >> 16) & 1u)) >> 16);
}

// ---------------- prep: convert A_w, B_w to bf16 (vectorized) ----------------
__global__ __launch_bounds__(256) void prep_kernel(
    const float* __restrict__ A_w, const float* __restrict__ B_w,
    unsigned short* __restrict__ Abf, unsigned short* __restrict__ Bbf) {
  int i4 = blockIdx.x * 256 + threadIdx.x;   // float4 index, total 2.1M/4 = 524288
  if (i4 < (BOT * IN_F) / 4) {
    float4 a = ((const float4*)A_w)[i4];
    float4 b = ((const float4*)B_w)[i4];
    ushort4 ha, hb;
    ha.x = f2bf_rne(a.x); ha.y = f2bf_rne(a.y); ha.z = f2bf_rne(a.z); ha.w = f2bf_rne(a.w);
    hb.x = f2bf_rne(b.x); hb.y = f2bf_rne(b.y); hb.z = f2bf_rne(b.z); hb.w = f2bf_rne(b.w);
    ((ushort4*)Abf)[i4] = ha;
    ((ushort4*)Bbf)[i4] = hb;
  }
}

// ---------------- router v2: fp64, register-blocked, also emits x_bf16 ----------------
// block 256 = 16 token-groups (2 tokens each) x 16 k-lanes; 32 tokens/block, grid 512
__global__ __launch_bounds__(256) void router_kernel(
    const float* __restrict__ x, const float* __restrict__ Wq,
    const float* __restrict__ keys, float* __restrict__ gate,
    unsigned short* __restrict__ x_bf) {
  __shared__ double wq_sc[16 * 256];   // wq chunk [16][256]; later reused as sc[32][65]
  __shared__ double q_s[32 * 17];      // padded: stride 17 doubles -> conflict-free
  __shared__ double keys_s[64 * 16];
  const int tid = threadIdx.x;
  const int tg = tid >> 4, kl = tid & 15;
  const size_t t0 = (size_t)blockIdx.x * 32;
  const int ta = tg * 2, tb = ta + 1;

  for (int i = tid; i < NE * RD; i += 256) keys_s[i] = (double)keys[i];

  double acc[2][16];
#pragma unroll
  for (int r = 0; r < 16; r++) { acc[0][r] = 0.0; acc[1][r] = 0.0; }

  const float* xa = x + (t0 + ta) * IN_F;
  const float* xb = x + (t0 + tb) * IN_F;
  unsigned short* xba = x_bf + (t0 + ta) * IN_F;
  unsigned short* xbb = x_bf + (t0 + tb) * IN_F;

  for (int kc = 0; kc < IN_F; kc += 256) {
    __syncthreads();
#pragma unroll
    for (int i = 0; i < 16; i++) {
      int f = i * 256 + tid;            // f = row*256 + col, row<16, col<256
      int row = f >> 8, col = f & 255;
      wq_sc[f] = (double)Wq[row * IN_F + kc + col];
    }
    __syncthreads();
#pragma unroll
    for (int s = 0; s < 8; s++) {
      int c = kc + s * 32 + kl * 2;     // this lane owns 2 consecutive columns
      float2 va = *(const float2*)(xa + c);
      float2 vb = *(const float2*)(xb + c);
      ushort2 ha, hb;
      ha.x = f2bf_rne(va.x); ha.y = f2bf_rne(va.y);
      hb.x = f2bf_rne(vb.x); hb.y = f2bf_rne(vb.y);
      *(ushort2*)(xba + c) = ha;
      *(ushort2*)(xbb + c) = hb;
      double a0 = (double)va.x, a1 = (double)va.y;
      double b0 = (double)vb.x, b1 = (double)vb.y;
      const double* wp = wq_sc + s * 32 + kl * 2;  // 16B lane stride -> 2-way (free)
#pragma unroll
      for (int r = 0; r < 16; r++) {
        double w0 = wp[r * 256], w1 = wp[r * 256 + 1];
        acc[0][r] += a0 * w0 + a1 * w1;
        acc[1][r] += b0 * w0 + b1 * w1;
      }
    }
  }
  // reduce across the 16 k-lanes (adjacent lanes in wave)
#pragma unroll
  for (int m = 1; m <= 8; m <<= 1) {
#pragma unroll
    for (int r = 0; r < 16; r++) {
      acc[0][r] += __shfl_xor(acc[0][r], m, 64);
      acc[1][r] += __shfl_xor(acc[1][r], m, 64);
    }
  }
  if (kl == 0) {
#pragma unroll
    for (int r = 0; r < 16; r++) {
      q_s[ta * 17 + r] = acc[0][r];
      q_s[tb * 17 + r] = acc[1][r];
    }
  }
  __syncthreads();

  // phase 2: scores sc[32][65] (aliases wq_sc), fp64
  double* sc = wq_sc;
  {
    int t = tid & 31, eg = tid >> 5;    // 8 expert-groups x 8 experts
    double q[16];
#pragma unroll
    for (int r = 0; r < 16; r++) q[r] = q_s[t * 17 + r];
    for (int i = 0; i < 8; i++) {
      int e = eg * 8 + i;
      double s = 0.0;
#pragma unroll
      for (int r = 0; r < 16; r++) s += q[r] * keys_s[e * 16 + r];
      sc[t * 65 + e] = s;
    }
  }
  // zero the gate rows for this block
  {
    float4 z4 = make_float4(0.f, 0.f, 0.f, 0.f);
    float4* grow4 = (float4*)(gate + t0 * NE);
    for (int i = tid; i < 32 * NE / 4; i += 256) grow4[i] = z4;
  }
  __syncthreads();

  // phase 3: top-16 (ties -> lowest index), softmax (fp64), scatter
  if (tid < 32) {
    int t = tid;
    double vals[16]; int idx[16];
    unsigned long long used = 0ull;
    for (int s = 0; s < 16; s++) {
      double best = -1e300; int bi = 0;
      for (int e = 0; e < 64; e++) {
        double v = sc[t * 65 + e];
        if (!((used >> e) & 1ull) && v > best) { best = v; bi = e; }
      }
      used |= (1ull << bi);
      vals[s] = best; idx[s] = bi;
    }
    double mx = vals[0], sum = 0.0, w[16];
    for (int i = 0; i < 16; i++) { w[i] = exp(vals[i] - mx); sum += w[i]; }
    double inv = 1.0 / sum;
    float* gr = gate + (t0 + t) * NE;
    for (int i = 0; i < 16; i++) gr[idx[i]] = (float)(w[i] * inv);
  }
}

// ---------------- stage A: z[16384,512] = (x_bf @ A^T) * gate, bf16 out ----------------
// 128x128 tile, BK=32, LDS rows padded to 40 bf16 (conflict-free frag reads)
__global__ __launch_bounds__(256) void stageA_kernel(
    const unsigned short* __restrict__ x_bf, const unsigned short* __restrict__ Abf,
    const float* __restrict__ gate, unsigned short* __restrict__ z) {
  __shared__ unsigned short As[128 * 40];
  __shared__ unsigned short Bs[128 * 40];
  __shared__ float gl[128 * 16];
  const int tid = threadIdx.x;
  const int bid = blockIdx.x;
  const int mt = (bid & 7) + (bid >> 5) * 8;   // XCD swizzle: same m-tile -> same XCD
  const int nt = (bid >> 3) & 3;
  const size_t m0 = (size_t)mt * 128;
  const int n0 = nt * 128;

  for (int i = 0; i < 8; i++) {
    int f = i * 256 + tid;
    gl[f] = gate[(m0 + (f >> 4)) * NE + (n0 >> 3) + (f & 15)];
  }
  const int wid = tid >> 6, lane = tid & 63;
  const int wm = (wid & 1) * 64, wn = (wid >> 1) * 64;
  const int lr = lane & 15, lq = lane >> 4;
  floatx4 acc[4][4];
  for (int i = 0; i < 4; i++)
    for (int j = 0; j < 4; j++) acc[i][j] = 0.0f;

  for (int k0 = 0; k0 < IN_F; k0 += 32) {
    __syncthreads();
    for (int p = 0; p < 2; p++) {
      int f = p * 256 + tid;
      int row = f >> 2, c8 = (f & 3) * 8;
      *(float4*)(As + row * 40 + c8) =
          *(const float4*)(x_bf + (m0 + row) * IN_F + k0 + c8);
      *(float4*)(Bs + row * 40 + c8) =
          *(const float4*)(Abf + (size_t)(n0 + row) * IN_F + k0 + c8);
    }
    __syncthreads();
    short8 a[4], b[4];
    for (int i = 0; i < 4; i++) a[i] = *(const short8*)(As + (wm + i * 16 + lr) * 40 + lq * 8);
    for (int j = 0; j < 4; j++) b[j] = *(const short8*)(Bs + (wn + j * 16 + lr) * 40 + lq * 8);
    for (int i = 0; i < 4; i++)
      for (int j = 0; j < 4; j++)
        acc[i][j] = __builtin_amdgcn_mfma_f32_16x16x32_bf16(a[i], b[j], acc[i][j], 0, 0, 0);
  }
  for (int i = 0; i < 4; i++) {
    for (int j = 0; j < 4; j++) {
      int cl = wn + j * 16 + lr;
      int el = cl >> 3;
      for (int g = 0; g < 4; g++) {
        int rl = wm + i * 16 + lq * 4 + g;
        float v = acc[i][j][g] * gl[rl * 16 + el];
        z[(m0 + rl) * BOT + n0 + cl] = f2bf_rne(v);
      }
    }
  }
}

// ---------------- stage B: out[16384,4096] = z @ B^T * 2.0 ----------------
__global__ __launch_bounds__(256) void stageB_kernel(
    const unsigned short* __restrict__ z, const unsigned short* __restrict__ Bbf,
    float* __restrict__ out) {
  __shared__ unsigned short As[128 * 40];
  __shared__ unsigned short Bs[128 * 40];
  const int tid = threadIdx.x;
  const int bid = blockIdx.x;
  const int mt = (bid & 7) + (bid >> 8) * 8;   // XCD swizzle
  const int nt = (bid >> 3) & 31;
  const size_t m0 = (size_t)mt * 128;
  const int n0 = nt * 128;
  const int wid = tid >> 6, lane = tid & 63;
  const int wm = (wid & 1) * 64, wn = (wid >> 1) * 64;
  const int lr = lane & 15, lq = lane >> 4;
  floatx4 acc[4][4];
  for (int i = 0; i < 4; i++)
    for (int j = 0; j < 4; j++) acc[i][j] = 0.0f;

  for (int k0 = 0; k0 < BOT; k0 += 32) {
    __syncthreads();
    for (int p = 0; p < 2; p++) {
      int f = p * 256 + tid;
      int row = f >> 2, c8 = (f & 3) * 8;
      *(float4*)(As + row * 40 + c8) =
          *(const float4*)(z + (m0 + row) * BOT + k0 + c8);
      *(float4*)(Bs + row * 40 + c8) =
          *(const float4*)(Bbf + (size_t)(n0 + row) * BOT + k0 + c8);
    }
    __syncthreads();
    short8 a[4], b[4];
    for (int i = 0; i < 4; i++) a[i] = *(const short8*)(As + (wm + i * 16 + lr) * 40 + lq * 8);
    for (int j = 0; j < 4; j++) b[j] = *(const short8*)(Bs + (wn + j * 16 + lr) * 40 + lq * 8);
    for (int i = 0; i < 4; i++)
      for (int j = 0; j < 4; j++)
        acc[i][j] = __builtin_amdgcn_mfma_f32_16x16x32_bf16(a[i], b[j], acc[i][j], 0, 0, 0);
  }
  for (int i = 0; i < 4; i++) {
    for (int j = 0; j < 4; j++) {
      int cl = wn + j * 16 + lr;
      for (int g = 0; g < 4; g++) {
        int rl = wm + i * 16 + lq * 4 + g;
        out[(m0 + rl) * OUT_F + n0 + cl] = acc[i][j][g] * 2.0f;  // SCALING = 32/16
      }
    }
  }
}

extern "C" void kernel_launch(void* const* d_in, const int* in_sizes, int n_in,
                              void* d_out, int out_size, void* d_ws, size_t ws_size,
                              hipStream_t stream) {
  const float* x    = (const float*)d_in[0];
  const float* A_w  = (const float*)d_in[1];
  const float* B_w  = (const float*)d_in[2];
  const float* Wq   = (const float*)d_in[3];
  const float* keys = (const float*)d_in[4];
  float* out = (float*)d_out;

  char* ws = (char*)d_ws;
  float* gate          = (float*)ws;                                   // 4 MB
  unsigned short* z    = (unsigned short*)(ws + (4 << 20));            // 16 MB
  unsigned short* Abf  = (unsigned short*)(ws + (4 << 20) + 16777216); // 4 MB
  unsigned short* Bbf  = Abf + BOT * IN_F;                             // 4 MB
  // x_bf (134 MB) lives in d_out (268 MB): router writes it, stageA reads it,
  // stageB then overwrites d_out with the final output.
  unsigned short* x_bf = (unsigned short*)d_out;

  hipLaunchKernelGGL(prep_kernel, dim3(2048), dim3(256), 0, stream, A_w, B_w, Abf, Bbf);
  hipLaunchKernelGGL(router_kernel, dim3(512), dim3(256), 0, stream, x, Wq, keys, gate, x_bf);
  hipLaunchKernelGGL(stageA_kernel, dim3(512), dim3(256), 0, stream, x_bf, Abf, gate, z);
  hipLaunchKernelGGL(stageB_kernel, dim3(4096), dim3(256), 0, stream, z, Bbf, out);
}